// Round 1
// baseline (523.873 us; speedup 1.0000x reference)
//
#include <hip/hip_runtime.h>
#include <hip/hip_bf16.h>
#include <cstdint>
#include <cstddef>

// LinOSS block: B=32, T=4096, H=256, S=256
// Pipeline:
//   prep:      weights fp32->bf16, coeff[s] = decay^2*cos(omega), cL[s]=coeff^64
//   ln:        x -> x_norm (bf16) in ws
//   gemm<0>:   u = x_norm @ W1^T  (bf16, ws)
//   scan_local: in-place chunked scan on u (64 chunks of 64 steps), carries
//   scan_carry: scan carries across chunks, write final_state to d_out tail
//   fixup:     in-place states = local + c^(i+1) * P_prev
//   gemm<1>:   mixed = gelu(states @ W2^T + direct*x_norm)  -> in-place into xn buffer
//   gemm<2>:   y = x + mixed @ W3^T + out_b  -> d_out (fp32)

typedef __bf16 bf16x8 __attribute__((ext_vector_type(8)));
typedef float f32x4 __attribute__((ext_vector_type(4)));

#define BB 32
#define TT 4096
#define HH 256
#define SS 256
#define MTOT (BB*TT)          // 131072
#define NCHUNK 64
#define CLEN 64               // TT / NCHUNK

__device__ __forceinline__ void gl_lds16(const void* g, void* l) {
    __builtin_amdgcn_global_load_lds((const __attribute__((address_space(1))) void*)g,
                                     (__attribute__((address_space(3))) void*)l, 16, 0, 0);
}

// ---------------- prep: weight cast + coeff ----------------
__global__ void prep_kernel(const float* __restrict__ w1, const float* __restrict__ w2,
                            const float* __restrict__ w3,
                            __bf16* __restrict__ w1b, __bf16* __restrict__ w2b,
                            __bf16* __restrict__ w3b,
                            const float* __restrict__ a_diag, const float* __restrict__ g_diag,
                            const float* __restrict__ dt,
                            float* __restrict__ coeff, float* __restrict__ cL) {
    int i = blockIdx.x * 256 + threadIdx.x;   // grid 256 -> 65536 threads
    w1b[i] = (__bf16)w1[i];
    w2b[i] = (__bf16)w2[i];
    w3b[i] = (__bf16)w3[i];
    if (i < SS) {
        float d = dt[i];
        float sp = (d > 20.f) ? d : log1pf(expf(d));      // softplus
        float dts = sp + 1e-4f;
        float omega = a_diag[i] * dts;
        float gg = g_diag[i];
        float spg = (gg > 20.f) ? gg : log1pf(expf(gg));
        float dec = expf(-spg * dts);
        float c = dec * dec * cosf(omega);
        coeff[i] = c;
        float p = c;
        #pragma unroll
        for (int q = 0; q < 6; ++q) p = p * p;            // c^64
        cL[i] = p;
    }
}

// ---------------- LayerNorm ----------------
__global__ __launch_bounds__(256) void ln_kernel(const float* __restrict__ x,
                          const float* __restrict__ w, const float* __restrict__ b,
                          __bf16* __restrict__ xn) {
    int row = blockIdx.x * 4 + (threadIdx.x >> 6);
    int lane = threadIdx.x & 63;
    size_t base = (size_t)row * HH + lane * 4;
    const float4 v = *(const float4*)&x[base];
    float s  = v.x + v.y + v.z + v.w;
    float ss = v.x*v.x + v.y*v.y + v.z*v.z + v.w*v.w;
    #pragma unroll
    for (int off = 32; off; off >>= 1) {
        s  += __shfl_xor(s,  off, 64);
        ss += __shfl_xor(ss, off, 64);
    }
    float mu  = s * (1.f/256.f);
    float var = ss * (1.f/256.f) - mu*mu;
    float sc  = rsqrtf(var + 1e-5f);
    const float4 wv = *(const float4*)&w[lane*4];
    const float4 bv = *(const float4*)&b[lane*4];
    union { __bf16 h[4]; uint2 u; } pk;
    pk.h[0] = (__bf16)((v.x - mu)*sc*wv.x + bv.x);
    pk.h[1] = (__bf16)((v.y - mu)*sc*wv.y + bv.y);
    pk.h[2] = (__bf16)((v.z - mu)*sc*wv.z + bv.z);
    pk.h[3] = (__bf16)((v.w - mu)*sc*wv.w + bv.w);
    *(uint2*)&xn[base] = pk.u;
}

// ---------------- MFMA GEMM: C[m,n] = sum_k A[m,k]*Bt[n,k] + epilogue ----------------
// M=131072, N=256, K=256. Tile 128x128, BK=64, 256 threads (4 waves, 2x2 of 64x64).
// XOR-swizzled LDS (granule kc ^ (row&7)) to kill ds_read_b128 bank conflicts while
// keeping global_load_lds's contiguous wave-uniform-base+lane*16 destination.
template<int MODE>
__global__ __launch_bounds__(256) void gemm_kernel(
    const __bf16* __restrict__ A, const __bf16* __restrict__ Bt,
    void* Cout,                    // MODE0: bf16 u; MODE1: bf16 mixed (aliases xn_in!); MODE2: f32 y
    const __bf16* xn_in,           // MODE1: x_norm (same buffer as Cout)
    const float* __restrict__ dvec,   // MODE1: direct[H]
    const float* __restrict__ xres,   // MODE2: x
    const float* __restrict__ bias)   // MODE2: out_b
{
    __shared__ __bf16 As[128*64];
    __shared__ __bf16 Bs[128*64];
    const int tid = threadIdx.x;
    const int lane = tid & 63;
    const int wid = tid >> 6;
    const int wm = wid >> 1, wn = wid & 1;
    const int quad = lane >> 4, l15 = lane & 15;
    const int bx = blockIdx.x & 1, by = blockIdx.x >> 1;
    const int m0 = by * 128, n0 = bx * 128;

    f32x4 acc[4][4] = {};

    for (int k0 = 0; k0 < 256; k0 += 64) {
        #pragma unroll
        for (int r = 0; r < 4; ++r) {
            int g = r * 256 + tid;          // granule 0..1023 (16B each)
            int row = g >> 3, c = g & 7;
            int kc = c ^ (row & 7);         // swizzled source k-granule
            gl_lds16(A  + (size_t)(m0 + row) * 256 + k0 + kc * 8, &As[g * 8]);
            gl_lds16(Bt + (size_t)(n0 + row) * 256 + k0 + kc * 8, &Bs[g * 8]);
        }
        __syncthreads();
        #pragma unroll
        for (int kk = 0; kk < 64; kk += 32) {
            const int gb = kk >> 3;         // 0 or 4
            bf16x8 af[4], bfr[4];
            #pragma unroll
            for (int i = 0; i < 4; ++i) {
                int m = wm * 64 + i * 16 + l15;
                af[i]  = *(const bf16x8*)&As[(m * 8 + ((gb + quad) ^ (m & 7))) * 8];
                int n = wn * 64 + i * 16 + l15;
                bfr[i] = *(const bf16x8*)&Bs[(n * 8 + ((gb + quad) ^ (n & 7))) * 8];
            }
            #pragma unroll
            for (int i = 0; i < 4; ++i)
                #pragma unroll
                for (int j = 0; j < 4; ++j)
                    acc[i][j] = __builtin_amdgcn_mfma_f32_16x16x32_bf16(af[i], bfr[j], acc[i][j], 0, 0, 0);
        }
        __syncthreads();
    }

    #pragma unroll
    for (int i = 0; i < 4; ++i) {
        #pragma unroll
        for (int j = 0; j < 4; ++j) {
            int n = n0 + wn * 64 + j * 16 + l15;
            #pragma unroll
            for (int r = 0; r < 4; ++r) {
                int m = m0 + wm * 64 + i * 16 + quad * 4 + r;
                size_t idx = (size_t)m * 256 + n;
                float v = acc[i][j][r];
                if (MODE == 0) {
                    ((__bf16*)Cout)[idx] = (__bf16)v;
                } else if (MODE == 1) {
                    v += dvec[n] * (float)xn_in[idx];   // read-before-write, same lane, same elem
                    float t = tanhf(0.7978845608028654f * (v + 0.044715f * v * v * v));
                    ((__bf16*)Cout)[idx] = (__bf16)(0.5f * v * (1.0f + t));
                } else {
                    ((float*)Cout)[idx] = xres[idx] + v + bias[n];
                }
            }
        }
    }
}

// ---------------- chunked scan ----------------
// blockIdx.x = chunk, blockIdx.y = b, thread = s. In-place on u (bf16).
__global__ __launch_bounds__(256) void scan_local(__bf16* u, const float* __restrict__ coeff,
                           const float* __restrict__ state0, float* __restrict__ carry) {
    int ch = blockIdx.x, b = blockIdx.y, s = threadIdx.x;
    float c = coeff[s];
    float st = (ch == 0) ? state0[b * SS + s] : 0.f;
    size_t base = ((size_t)b * TT + (size_t)ch * CLEN) * SS + s;
    #pragma unroll 8
    for (int i = 0; i < CLEN; ++i) {
        float v = (float)u[base + (size_t)i * SS];
        st = c * st + v;
        u[base + (size_t)i * SS] = (__bf16)st;
    }
    carry[(b * NCHUNK + ch) * SS + s] = st;
}

// one block per b; sequential scan over 64 chunk carries, in-place -> prefix states
__global__ __launch_bounds__(256) void scan_carry(float* carry, const float* __restrict__ cL,
                           float* __restrict__ fs_out) {
    int b = blockIdx.x, s = threadIdx.x;
    float cl = cL[s];
    float P = 0.f;
    for (int j = 0; j < NCHUNK; ++j) {
        int idx = (b * NCHUNK + j) * SS + s;
        P = cl * P + carry[idx];
        carry[idx] = P;
    }
    fs_out[b * SS + s] = P;   // final_state = state at t = T-1
}

// blockIdx.x = ch-1 (chunks 1..63), blockIdx.y = b
__global__ __launch_bounds__(256) void fixup_kernel(__bf16* u, const float* __restrict__ coeff,
                             const float* __restrict__ carry) {
    int ch = blockIdx.x + 1, b = blockIdx.y, s = threadIdx.x;
    float c = coeff[s];
    float P = carry[(b * NCHUNK + ch - 1) * SS + s];
    float pw = c;
    size_t base = ((size_t)b * TT + (size_t)ch * CLEN) * SS + s;
    #pragma unroll 8
    for (int i = 0; i < CLEN; ++i) {
        float v = (float)u[base + (size_t)i * SS] + pw * P;
        u[base + (size_t)i * SS] = (__bf16)v;
        pw *= c;
    }
}

extern "C" void kernel_launch(void* const* d_in, const int* in_sizes, int n_in,
                              void* d_out, int out_size, void* d_ws, size_t ws_size,
                              hipStream_t stream) {
    const float* x      = (const float*)d_in[0];
    const float* state0 = (const float*)d_in[1];
    const float* w1     = (const float*)d_in[2];   // in_to_state [S,H]
    const float* w2     = (const float*)d_in[3];   // state_to_hidden [H,S]
    const float* direct = (const float*)d_in[4];
    const float* a_diag = (const float*)d_in[5];
    const float* g_diag = (const float*)d_in[6];
    const float* dt     = (const float*)d_in[7];
    const float* norm_w = (const float*)d_in[8];
    const float* norm_b = (const float*)d_in[9];
    const float* w3     = (const float*)d_in[10];  // out_w [H,H]
    const float* out_b  = (const float*)d_in[11];

    char* ws = (char*)d_ws;
    const size_t MH2 = (size_t)MTOT * HH * 2;      // 67108864
    __bf16* xn    = (__bf16*)(ws);                  // [M,H] bf16 (later holds mixed)
    __bf16* u     = (__bf16*)(ws + MH2);            // [M,S] bf16 (u -> local -> states)
    __bf16* w1b   = (__bf16*)(ws + 2*MH2);
    __bf16* w2b   = (__bf16*)(ws + 2*MH2 + 131072);
    __bf16* w3b   = (__bf16*)(ws + 2*MH2 + 262144);
    float*  coeff = (float*)(ws + 2*MH2 + 393216);
    float*  cL    = (float*)(ws + 2*MH2 + 394240);
    float*  carry = (float*)(ws + 2*MH2 + 395264);  // [B, NCHUNK, S] f32 = 2MB

    float* y_out  = (float*)d_out;
    float* fs_out = (float*)d_out + (size_t)MTOT * HH;

    prep_kernel<<<256, 256, 0, stream>>>(w1, w2, w3, w1b, w2b, w3b,
                                         a_diag, g_diag, dt, coeff, cL);
    ln_kernel<<<MTOT/4, 256, 0, stream>>>(x, norm_w, norm_b, xn);
    gemm_kernel<0><<<2048, 256, 0, stream>>>(xn, w1b, u, nullptr, nullptr, nullptr, nullptr);
    scan_local<<<dim3(NCHUNK, BB), 256, 0, stream>>>(u, coeff, state0, carry);
    scan_carry<<<BB, 256, 0, stream>>>(carry, cL, fs_out);
    fixup_kernel<<<dim3(NCHUNK-1, BB), 256, 0, stream>>>(u, coeff, carry);
    gemm_kernel<1><<<2048, 256, 0, stream>>>(u, w2b, xn, xn, direct, nullptr, nullptr);
    gemm_kernel<2><<<2048, 256, 0, stream>>>(xn, w3b, y_out, nullptr, nullptr, x, out_b);
}